// Round 6
// baseline (5674.425 us; speedup 1.0000x reference)
//
#include <hip/hip_runtime.h>
#include <hip/hip_bf16.h>

#define BATCH 128
#define SEQ   1024
#define INDIM 256
#define HID   1024
#define NGATE 4096   // 4*HID
#define KTOT  1280   // INDIM + HID
#define OUTD  256
#define NKK   40     // total K-steps of 32 (1280/32)
#define XKK   8      // k-steps covering the x part (256/32)
#define HKK   32     // k-steps covering the h part
#define NBG   8      // batch groups
#define ROWS  16     // batch rows per group
#define NSL   32     // WGs per group
#define JCOLS 32     // h-columns per WG

typedef __attribute__((ext_vector_type(8))) short s16x8;
typedef __attribute__((ext_vector_type(4))) float f32x4;

__device__ __forceinline__ unsigned short f2bf(float f) {
    unsigned int u = __float_as_uint(f);
    u += 0x7FFFu + ((u >> 16) & 1u);
    return (unsigned short)(u >> 16);
}
__device__ __forceinline__ float sigmoidf_(float x) {
    return 1.0f / (1.0f + __expf(-x));
}
__device__ __forceinline__ float tanhf_(float x) {
    return 1.0f - 2.0f / (1.0f + __expf(2.0f * x));
}

// ---------------------------------------------------------------------------
// Prep 1: WT[n][k] bf16 (transposed, concatenated [Wx;Wh])
// ---------------------------------------------------------------------------
__global__ __launch_bounds__(256) void prep_wt(const float* __restrict__ Wx,
                                               const float* __restrict__ Wh,
                                               unsigned short* __restrict__ WT) {
    __shared__ float tile[64][65];
    int k0 = blockIdx.x * 64;
    int n0 = blockIdx.y * 64;
    for (int idx = threadIdx.x; idx < 64 * 64; idx += 256) {
        int kk = idx >> 6, nn = idx & 63;
        int k = k0 + kk;
        float v = (k < INDIM) ? Wx[(size_t)k * NGATE + (n0 + nn)]
                              : Wh[(size_t)(k - INDIM) * NGATE + (n0 + nn)];
        tile[kk][nn] = v;
    }
    __syncthreads();
    for (int idx = threadIdx.x; idx < 64 * 64; idx += 256) {
        int nn = idx >> 6, kk = idx & 63;
        WT[(size_t)(n0 + nn) * KTOT + (k0 + kk)] = f2bf(tile[kk][nn]);
    }
}

// ---------------------------------------------------------------------------
// Prep 2: x fp32 -> bf16; zero h0/h1; zero per-wave flags.
// ---------------------------------------------------------------------------
__global__ __launch_bounds__(256) void prep_x(const float* __restrict__ x,
                                              unsigned short* __restrict__ xb,
                                              unsigned short* __restrict__ h0,
                                              unsigned short* __restrict__ h1,
                                              unsigned int* __restrict__ flags) {
    int gid = blockIdx.x * blockDim.x + threadIdx.x;
    int stride = gridDim.x * blockDim.x;
    const int N4 = BATCH * SEQ * INDIM / 4;
    const float4* xv = reinterpret_cast<const float4*>(x);
    uint2* xo = reinterpret_cast<uint2*>(xb);
    for (int i = gid; i < N4; i += stride) {
        float4 v = xv[i];
        uint2 o;
        o.x = (unsigned)f2bf(v.x) | ((unsigned)f2bf(v.y) << 16);
        o.y = (unsigned)f2bf(v.z) | ((unsigned)f2bf(v.w) << 16);
        xo[i] = o;
    }
    const int NH = BATCH * HID;
    for (int i = gid; i < NH; i += stride) {
        h0[i] = 0;
        h1[i] = 0;
    }
    // flags: 256 WG x 8 waves x 16 uints (64B padded) = 32768 uints
    for (int i = gid; i < 32768; i += stride) flags[i] = 0;
}

// ---------------------------------------------------------------------------
// Persistent LSTM: 256 WGs x 512 threads (8 waves). WG=(bg,ns): rows
// bg*16..+16, h-cols ns*32..+32, 4 gates. Wave = (gate = w>>1, colhalf = w&1)
// -> ONE 16x16 tile, B-frags = 40 x s16x8 = 160 VGPR: truly register-resident.
// Per-wave flags (agent scope, 64B padded); 2 barriers/step.
// ---------------------------------------------------------------------------
__global__ __launch_bounds__(512, 2) void lstm_persist(
    const unsigned short* __restrict__ xb,   // [B][S][INDIM] bf16
    const unsigned short* __restrict__ WT,   // [NGATE][KTOT] bf16
    unsigned short* __restrict__ h0,         // [B][HID] bf16 (zeroed)
    unsigned short* __restrict__ h1,         // [B][HID] bf16 (zeroed)
    unsigned int* __restrict__ flags,        // [256*8] x 16 uints (zeroed)
    const float* __restrict__ bias) {        // [NGATE]

    __shared__ unsigned short xbuf0[XKK * 512];  // 8 KB, swizzled slots
    __shared__ unsigned short xbuf1[XKK * 512];  // 8 KB
    __shared__ unsigned short hbuf[HKK * 512];   // 32 KB, swizzled slots
    __shared__ float gex[4 * ROWS * JCOLS];      // 8 KB

    const int tid  = threadIdx.x;
    const int wave = tid >> 6, lane = tid & 63;
    const int lr = lane & 15, kq = lane >> 4;
    const int bg = blockIdx.x & 7;
    const int ns = blockIdx.x >> 3;
    const int b0 = bg * ROWS;
    const int j0 = ns * JCOLS;
    const int g  = wave >> 1;    // gate
    const int ch = wave & 1;     // column half

    // ---- B fragments: ONE tile (gate g, cols j0+ch*16..+16), full K ----
    s16x8 br[NKK];
    {
        const unsigned short* bbase =
            WT + ((size_t)(g * HID + j0 + ch * 16 + lr)) * KTOT + kq * 8;
#pragma unroll
        for (int kk = 0; kk < NKK; kk++)
            br[kk] = *reinterpret_cast<const s16x8*>(bbase + kk * 32);
    }

    // ---- epilogue constants: 512 threads, 1 cell each ----
    const int erow = tid >> 5, ecol = tid & 31;
    const int j = j0 + ecol;
    const float bf_ = bias[0 * HID + j], bi_ = bias[1 * HID + j],
                bg_ = bias[2 * HID + j], bo_ = bias[3 * HID + j];
    float c = 0.f;

    // ---- x staging: wave stages slice kk=wave (linear dest, inv-swz src) ----
    const int srow = lane >> 2;
    const int skq = ((lane & 3) - ((lane >> 3) & 3)) & 3;
    const unsigned short* xsrc =
        xb + (size_t)(b0 + srow) * SEQ * INDIM + wave * 32 + skq * 8;

    // ---- MFMA A-read slot for lane (lr,kq) ----
    const int p_l = lr * 4 + ((kq + (lr >> 1)) & 3);

    // ---- h load/scatter: wave covers slices 4w..4w+3 ----
    const int hsl = 4 * wave + (lane >> 4);   // slice (== producer ns)
    const int hsub = lane & 15;               // row within slice
    const size_t hsrcoff = (size_t)(b0 + hsub) * HID + hsl * 32;  // shorts

    // ---- flags: mine; poll = producers 4w..4w+3 x 8 wave-flags (lanes<32) --
    unsigned int* wflag = flags + ((size_t)(bg * NSL + ns) * 8 + wave) * 16;
    const unsigned int* pflag =
        flags + ((size_t)(bg * NSL + 4 * wave + ((lane >> 3) & 3)) * 8 + (lane & 7)) * 16;

    // ---- prologue: stage x for t=0 ----
    __builtin_amdgcn_global_load_lds(
        (const __attribute__((address_space(1))) void*)xsrc,
        (__attribute__((address_space(3))) void*)(xbuf0 + wave * 512), 16, 0, 0);
    __syncthreads();

    for (int t = 0; t < SEQ; t++) {
        const unsigned short* hin = (t & 1) ? h1 : h0;
        unsigned short* hout      = (t & 1) ? h0 : h1;
        unsigned short* xcur      = (t & 1) ? xbuf1 : xbuf0;
        unsigned short* xnxt      = (t & 1) ? xbuf0 : xbuf1;

        // ---- per-wave poll: my 4 producers' 8 wave-flags >= t ----
        if (t > 0) {
            for (;;) {
                unsigned v = 0xFFFFFFFFu;
                if (lane < 32)
                    v = __hip_atomic_load(pflag, __ATOMIC_RELAXED,
                                          __HIP_MEMORY_SCOPE_AGENT);
                if (__all((int)(v >= (unsigned)t))) break;
                __builtin_amdgcn_s_sleep(1);
            }
        }

        // ---- issue h loads (latency hidden under x-MFMA) ----
        unsigned long long hv[8];
        {
            const unsigned long long* src =
                (const unsigned long long*)(hin + hsrcoff);
#pragma unroll
            for (int i = 0; i < 8; i++)
                hv[i] = __hip_atomic_load(src + i, __ATOMIC_RELAXED,
                                          __HIP_MEMORY_SCOPE_AGENT);
        }

        // ---- x-part MFMA (2 independent chains) ----
        f32x4 accA = {0.f, 0.f, 0.f, 0.f};
        f32x4 accB = {0.f, 0.f, 0.f, 0.f};
        {
            const unsigned short* ax = xcur + p_l * 8;
#pragma unroll
            for (int kk = 0; kk < XKK; kk += 2) {
                s16x8 a0 = *reinterpret_cast<const s16x8*>(ax + kk * 512);
                s16x8 a1 = *reinterpret_cast<const s16x8*>(ax + (kk + 1) * 512);
                accA = __builtin_amdgcn_mfma_f32_16x16x32_bf16(a0, br[kk], accA, 0, 0, 0);
                accB = __builtin_amdgcn_mfma_f32_16x16x32_bf16(a1, br[kk + 1], accB, 0, 0, 0);
            }
        }

        // ---- fire-and-forget: stage x for t+1 ----
        if (t + 1 < SEQ) {
            __builtin_amdgcn_global_load_lds(
                (const __attribute__((address_space(1))) void*)(xsrc + (size_t)(t + 1) * INDIM),
                (__attribute__((address_space(3))) void*)(xnxt + wave * 512), 16, 0, 0);
        }

        // ---- scatter h to swizzled LDS slots ----
#pragma unroll
        for (int i = 0; i < 8; i++) {
            int kqi = i >> 1;
            int p = hsub * 4 + ((kqi + (hsub >> 1)) & 3);
            *(unsigned long long*)(hbuf + hsl * 512 + p * 8 + (i & 1) * 4) = hv[i];
        }
        __syncthreads();   // B2: hbuf + x stage complete

        // ---- h-part MFMA ----
        {
            const unsigned short* ah = hbuf + p_l * 8;
#pragma unroll
            for (int kk = 0; kk < HKK; kk += 2) {
                s16x8 a0 = *reinterpret_cast<const s16x8*>(ah + kk * 512);
                s16x8 a1 = *reinterpret_cast<const s16x8*>(ah + (kk + 1) * 512);
                accA = __builtin_amdgcn_mfma_f32_16x16x32_bf16(a0, br[XKK + kk], accA, 0, 0, 0);
                accB = __builtin_amdgcn_mfma_f32_16x16x32_bf16(a1, br[XKK + kk + 1], accB, 0, 0, 0);
            }
        }
        f32x4 acc = accA + accB;

        // ---- gate exchange (C/D: col=lane&15, row=(lane>>4)*4+r) ----
#pragma unroll
        for (int r = 0; r < 4; r++)
            gex[g * 512 + (kq * 4 + r) * 32 + ch * 16 + lr] = acc[r];
        __syncthreads();   // B3: gex ready

        // ---- activations + c update + h store (1 cell/thread) ----
        {
            float ff = sigmoidf_(gex[0 * 512 + erow * 32 + ecol] + bf_);
            float ii = sigmoidf_(gex[1 * 512 + erow * 32 + ecol] + bi_);
            float gg = tanhf_(gex[2 * 512 + erow * 32 + ecol] + bg_);
            float oo = sigmoidf_(gex[3 * 512 + erow * 32 + ecol] + bo_);
            c = ff * c + ii * gg;
            unsigned short hvs = f2bf(oo * tanhf_(c));
            __hip_atomic_store(hout + (size_t)(b0 + erow) * HID + j, hvs,
                               __ATOMIC_RELAXED, __HIP_MEMORY_SCOPE_AGENT);
        }

        // ---- per-wave publish: drain own stores, then wave-flag = t+1 ----
        asm volatile("s_waitcnt vmcnt(0)" ::: "memory");
        if (lane == 0)
            __hip_atomic_store(wflag, (unsigned)(t + 1), __ATOMIC_RELAXED,
                               __HIP_MEMORY_SCOPE_AGENT);
    }
}

// ---------------------------------------------------------------------------
// Final FC
// ---------------------------------------------------------------------------
__global__ __launch_bounds__(256) void final_fc(const unsigned short* __restrict__ h,
                                                const float* __restrict__ Wfc,
                                                const float* __restrict__ bfc,
                                                float* __restrict__ out) {
    int b = blockIdx.x;
    int o = threadIdx.x;
    const unsigned short* hr = h + (size_t)b * HID;
    float acc = bfc[o];
#pragma unroll 8
    for (int k = 0; k < HID; k++) {
        acc += __uint_as_float(((unsigned)hr[k]) << 16) * Wfc[(size_t)k * OUTD + o];
    }
    out[(size_t)b * OUTD + o] = acc;
}

// ---------------------------------------------------------------------------
extern "C" void kernel_launch(void* const* d_in, const int* in_sizes, int n_in,
                              void* d_out, int out_size, void* d_ws, size_t ws_size,
                              hipStream_t stream) {
    const float* x    = (const float*)d_in[0];
    const float* Wx   = (const float*)d_in[1];
    const float* Wh   = (const float*)d_in[2];
    const float* bias = (const float*)d_in[3];
    const float* Wfc  = (const float*)d_in[4];
    const float* bfc  = (const float*)d_in[5];
    float* out = (float*)d_out;

    char* ws = (char*)d_ws;
    // ws layout (bytes):
    //   WT    : 4096*1280*2    = 10,485,760  @ 0
    //   xb    : 128*1024*256*2 = 67,108,864  @ 10,485,760
    //   h0    : 128*1024*2     =    262,144  @ 77,594,624
    //   h1    : 128*1024*2     =    262,144  @ 77,856,768
    //   flags : 32768*4        =    131,072  @ 78,118,912  -> 78,249,984 total
    unsigned short* WT  = (unsigned short*)(ws);
    unsigned short* xb  = (unsigned short*)(ws + 10485760);
    unsigned short* h0  = (unsigned short*)(ws + 77594624);
    unsigned short* h1  = (unsigned short*)(ws + 77856768);
    unsigned int* flags = (unsigned int*)(ws + 78118912);

    hipLaunchKernelGGL(prep_wt, dim3(KTOT / 64, NGATE / 64), dim3(256), 0, stream,
                       Wx, Wh, WT);
    hipLaunchKernelGGL(prep_x, dim3(1024), dim3(256), 0, stream, x, xb, h0, h1, flags);

    hipLaunchKernelGGL(lstm_persist, dim3(256), dim3(512), 0, stream,
                       xb, WT, h0, h1, flags, bias);

    // 1024 steps -> final h lands in h0
    hipLaunchKernelGGL(final_fc, dim3(128), dim3(256), 0, stream, h0, Wfc, bfc, out);
}